// Round 7
// baseline (159.971 us; speedup 1.0000x reference)
//
#include <hip/hip_runtime.h>
#include <hip/hip_bf16.h>

// SAGAN self-attention, MI355X (gfx950).
// B=4, H=W=64 (N=4096), C=128, d_qk=16. out = gamma * softmax(QK^T) V + x.
//
//  k1 qkv_proj : MFMA GEMM x[16384,128] @ [wq|wk|wv] -> Qb,Kb bf16 [4,4096,16],
//                Vt bf16 [4,128,4096] (transposed). Q pre-scaled by log2(e).
//  k2 attn     : flash attention, mfma_f32_32x32x16_bf16, swapped QK^T.
//                No max tracking: p = exp2(s - 16) (|s·log2e| << 127, softmax
//                shift-invariant; bias folded into QK MFMA C operand).
//                V staged via global_load_lds (linear LDS + XOR-swizzled source,
//                swizzled ds_read). K global->reg prefetch. Regs <= 128 for
//                4 waves/SIMD (launch_bounds(256,4)). NKS k-split bf16 partials.
//  k3 combine  : out = gamma * (sum_p O_p) / (sum_p l_p) + x.

typedef __attribute__((ext_vector_type(4)))  short short4v;
typedef __attribute__((ext_vector_type(8)))  short short8;
typedef __attribute__((ext_vector_type(16))) float f32x16;
typedef unsigned short u16;

#define LOG2E 1.4426950408889634f

#define GLOAD_LDS16(g, l)                                                     \
  __builtin_amdgcn_global_load_lds(                                           \
      (const __attribute__((address_space(1))) void*)(g),                     \
      (__attribute__((address_space(3))) void*)(l), 16, 0, 0)

__device__ __forceinline__ u16 f2bf(float f) {
  __hip_bfloat16 h = __float2bfloat16(f);
  return __builtin_bit_cast(u16, h);
}
__device__ __forceinline__ float bf2f(u16 u) {
  unsigned v = (unsigned)u << 16;
  return __builtin_bit_cast(float, v);
}
// pack two positive f32 -> bf16x2 (round-half-up): 2 adds + 1 v_perm
__device__ __forceinline__ unsigned pkbf(float lo, float hi) {
  unsigned a = __builtin_bit_cast(unsigned, lo) + 0x8000u;
  unsigned b = __builtin_bit_cast(unsigned, hi) + 0x8000u;
  unsigned r;
  asm("v_perm_b32 %0, %1, %2, %3" : "=v"(r) : "v"(b), "v"(a), "s"(0x07060302u));
  return r;   // lo_bf16 | hi_bf16<<16
}
// cross-half (lane i <-> i+32) sum via permlane32_swap: pure VALU
__device__ __forceinline__ float xhalf_sum(float x) {
  float a = x, b = x;
  asm("v_permlane32_swap_b32 %0, %1" : "+v"(a), "+v"(b));
  return a + b;
}

// ---------------------------------------------------------------- kernel 1
// grid 128 = b(4) x rt(32): block computes rows [rt*128, +128) of batch b.
__global__ __launch_bounds__(256) void qkv_proj(
    const float* __restrict__ x,
    const float* __restrict__ wq, const float* __restrict__ bq,
    const float* __restrict__ wk, const float* __restrict__ bk,
    const float* __restrict__ wv, const float* __restrict__ bv,
    u16* __restrict__ Qb, u16* __restrict__ Kb, u16* __restrict__ Vt)
{
  __shared__ u16 xs[128 * 136];
  __shared__ u16 ws[160 * 136];
  const int tid = threadIdx.x;
  const int b   = blockIdx.x >> 5;
  const int n0  = (blockIdx.x & 31) * 128;

  const float4* xg = (const float4*)(x + ((size_t)b * 4096 + n0) * 128);
#pragma unroll
  for (int p = 0; p < 16; ++p) {
    int idx = tid + p * 256;              // 4096 float4s
    float4 v = xg[idx];
    int n = idx >> 5, i4 = idx & 31;
    short4v pk;
    pk[0] = (short)f2bf(v.x); pk[1] = (short)f2bf(v.y);
    pk[2] = (short)f2bf(v.z); pk[3] = (short)f2bf(v.w);
    *(short4v*)(xs + n * 136 + i4 * 4) = pk;
  }
#pragma unroll
  for (int p = 0; p < 8; ++p) {
    int idx = tid + p * 256;              // 2048 = 128x16
    int k = idx >> 4, d = idx & 15;
    ws[d * 136 + k]        = f2bf(wq[idx] * LOG2E);
    ws[(16 + d) * 136 + k] = f2bf(wk[idx]);
  }
#pragma unroll
  for (int p = 0; p < 64; ++p) {
    int idx = tid + p * 256;              // 16384 = 128x128
    int k = idx >> 7, c = idx & 127;
    ws[(32 + c) * 136 + k] = f2bf(wv[idx]);
  }
  __syncthreads();

  const int lane = tid & 63, wid = tid >> 6;
  const int ln31 = lane & 31, hi = lane >> 5;

#pragma unroll
  for (int j = 0; j < 5; ++j) {
    int t  = wid + j * 4;                 // 0..19
    int mt = t / 5, nt = t % 5;
    const u16* arow = xs + (mt * 32 + ln31) * 136 + hi * 8;
    const u16* brow = ws + (nt * 32 + ln31) * 136 + hi * 8;
    f32x16 acc = (f32x16)0.0f;
#pragma unroll
    for (int ks = 0; ks < 8; ++ks) {
      short8 a = *(const short8*)(arow + ks * 16);
      short8 w = *(const short8*)(brow + ks * 16);
      acc = __builtin_amdgcn_mfma_f32_32x32x16_bf16(a, w, acc, 0, 0, 0);
    }
    if (nt == 0) {
      float bias = (ln31 < 16) ? bq[ln31] * LOG2E : bk[ln31 & 15];
      u16* base = ((ln31 < 16) ? Qb : Kb)
                + ((size_t)b * 4096 + n0 + mt * 32) * 16 + (ln31 & 15);
#pragma unroll
      for (int r = 0; r < 16; ++r) {
        int nl = (r & 3) + 8 * (r >> 2) + 4 * hi;   // C/D row map
        base[nl * 16] = f2bf(acc[r] + bias);
      }
    } else {
      int c = (nt - 1) * 32 + ln31;
      float bias = bv[c];
      u16* vb = Vt + ((size_t)b * 128 + c) * 4096 + n0 + mt * 32 + 4 * hi;
#pragma unroll
      for (int g = 0; g < 4; ++g) {
        short4v pk;
        pk[0] = (short)f2bf(acc[g*4+0] + bias);
        pk[1] = (short)f2bf(acc[g*4+1] + bias);
        pk[2] = (short)f2bf(acc[g*4+2] + bias);
        pk[3] = (short)f2bf(acc[g*4+3] + bias);
        *(short4v*)(vb + 8 * g) = pk;
      }
    }
  }
}

// ---------------------------------------------------------------- kernel 2
// grid 4*32*NKS. block 256 = 4 waves, wave owns 32 q-rows (128 q/block).
// Block handles k range [ks*4096/NKS, +4096/NKS) in 64-k chunks.
// V LDS tile: linear [128 rows][128 B], 16B-slot swizzle col16 ^= (row&7)
// applied on BOTH the global source address and the ds_read (rule #21).
template<int NKS>
__global__ __launch_bounds__(256, 4) void attn(
    const u16* __restrict__ Qb, const u16* __restrict__ Kb,
    const u16* __restrict__ Vt,
    u16* __restrict__ Ob, float* __restrict__ Lp)
{
  __shared__ __align__(16) char sm[2][16384];
  const int tid  = threadIdx.x;
  const int lane = tid & 63;
  const int wid  = tid >> 6;
  const int ln31 = lane & 31;
  const int hi   = lane >> 5;

  constexpr int KSH    = (NKS == 8) ? 3 : (NKS == 4) ? 2 : 1;
  constexpr int CHUNKS = 64 / NKS;        // 64-k chunks per block
  const int b   = blockIdx.x >> (5 + KSH);
  const int qt  = (blockIdx.x >> KSH) & 31;
  const int ks  = blockIdx.x & (NKS - 1);
  const int qw  = qt * 128 + wid * 32;    // wave's first q row (within batch)
  const int kb0 = ks * (4096 / NKS);

  // Q B-fragment: col q = ln31, d = hi*8 + j (Q pre-scaled by log2e)
  const short8 qf = *(const short8*)(Qb + (((size_t)b * 4096 + qw + ln31) << 4) + (hi << 3));

  f32x16 acc[4];
#pragma unroll
  for (int ct = 0; ct < 4; ++ct) acc[ct] = (f32x16)0.0f;
  float lacc = 0.f;
  const f32x16 cbias = (f32x16)(-16.0f);  // s = q.k*log2e - 16, free in MFMA C

  const char* kg = (const char*)(Kb + (size_t)b * 4096 * 16);
  // per-lane swizzled V source: row = wid*32 + (lane>>3) (+8 per call),
  // col16 = (lane&7) ^ (lane>>3)  [row&7 == lane>>3 for all calls]
  const char* vsrc = (const char*)(Vt + (size_t)b * 128 * 4096)
                   + (size_t)(wid * 32 + (lane >> 3)) * 8192
                   + (((lane & 7) ^ (lane >> 3)) << 4)
                   + (size_t)kb0 * 2;

  uint4 rkc0, rkc1, rkn0, rkn1;           // K fragments: current / next chunk

  auto stageV = [&](char* buf, int it) {  // DMA: 4 x 1KB per wave, linear dest
    char* ldst = buf + wid * 4096;
    const char* g = vsrc + (size_t)it * 128;
#pragma unroll
    for (int c = 0; c < 4; ++c)
      GLOAD_LDS16(g + c * 65536, ldst + c * 1024);
  };
  auto loadK = [&](int kb, uint4& k0, uint4& k1) {
    const char* kr = kg + (size_t)(kb + ln31) * 32 + hi * 16;
    k0 = *(const uint4*)(kr);             // kt=0 rows
    k1 = *(const uint4*)(kr + 1024);      // kt=1 rows
  };

  auto compute = [&](const char* buf, uint4 k0, uint4 k1) {
#pragma unroll
    for (int kt = 0; kt < 2; ++kt) {      // two independent 32-k subtiles
      // swapped QK^T: A = K rows (kk = ln31), B = Q -> D[kk][q], lane col = q
      short8 kf = __builtin_bit_cast(short8, kt ? k1 : k0);
      f32x16 s = __builtin_amdgcn_mfma_f32_32x32x16_bf16(kf, qf, cbias, 0, 0, 0);

      // p = exp2(s); s[r] is kk = (r&3)+8*(r>>2)+4*hi
      float p[16];
#pragma unroll
      for (int r = 0; r < 16; ++r) p[r] = exp2f(s[r]);
      float a0 = p[0]+p[1],  a1 = p[2]+p[3],  a2 = p[4]+p[5],  a3 = p[6]+p[7];
      float b0 = p[8]+p[9],  b1 = p[10]+p[11], b2 = p[12]+p[13], b3 = p[14]+p[15];
      lacc += ((a0+a1)+(a2+a3)) + ((b0+b1)+(b2+b3));

      // P -> bf16 PV A-fragments: cheap pack + permlane32_swap (T12)
      unsigned u0 = pkbf(p[0], p[1]),  u1 = pkbf(p[2], p[3]);
      unsigned u2 = pkbf(p[4], p[5]),  u3 = pkbf(p[6], p[7]);
      asm("v_permlane32_swap_b32 %0, %1" : "+v"(u0), "+v"(u2));
      asm("v_permlane32_swap_b32 %0, %1" : "+v"(u1), "+v"(u3));
      unsigned y0 = pkbf(p[8], p[9]),   y1 = pkbf(p[10], p[11]);
      unsigned y2 = pkbf(p[12], p[13]), y3 = pkbf(p[14], p[15]);
      asm("v_permlane32_swap_b32 %0, %1" : "+v"(y0), "+v"(y2));
      asm("v_permlane32_swap_b32 %0, %1" : "+v"(y1), "+v"(y3));
      union { unsigned u[4]; short8 s8; } pa0, pa1;
      pa0.u[0] = u0; pa0.u[1] = u1; pa0.u[2] = u2; pa0.u[3] = u3;
      pa1.u[0] = y0; pa1.u[1] = y1; pa1.u[2] = y2; pa1.u[3] = y3;

      // PV: acc[ct] += P[32q x 32k] @ V[32k x 32c]; swizzled b128 reads
      const int sw = ln31 & 7;
      __builtin_amdgcn_s_setprio(1);
#pragma unroll
      for (int ct = 0; ct < 4; ++ct) {
        const char* vrow = buf + (ct * 32 + ln31) * 128;
        short8 vf0 = *(const short8*)(vrow + (((kt * 4 + hi)     ^ sw) << 4));
        short8 vf1 = *(const short8*)(vrow + (((kt * 4 + hi + 2) ^ sw) << 4));
        acc[ct] = __builtin_amdgcn_mfma_f32_32x32x16_bf16(pa0.s8, vf0, acc[ct], 0, 0, 0);
        acc[ct] = __builtin_amdgcn_mfma_f32_32x32x16_bf16(pa1.s8, vf1, acc[ct], 0, 0, 0);
      }
      __builtin_amdgcn_s_setprio(0);
    }
  };

  stageV(sm[0], 0);
  loadK(kb0, rkc0, rkc1);
  __syncthreads();                        // drains DMA (vmcnt) + barrier
  int cur = 0;
#pragma unroll 1
  for (int it = 0; it < CHUNKS; ++it) {
    if (it < CHUNKS - 1) {                // issue next-chunk DMA + K prefetch
      stageV(sm[cur ^ 1], it + 1);
      loadK(kb0 + (it + 1) * 64, rkn0, rkn1);
    }
    compute(sm[cur], rkc0, rkc1);
    __syncthreads();                      // drain + barrier
    rkc0 = rkn0; rkc1 = rkn1; cur ^= 1;
  }

  // epilogue: cross-half l reduce, store bf16 partial O and l
  float lt = xhalf_sum(lacc);
  if (lane < 32)
    Lp[(size_t)ks * 16384 + (size_t)b * 4096 + qw + lane] = lt;
  u16* Op = Ob + ((size_t)ks * 16384 + (size_t)b * 4096 + qw) * 128;
#pragma unroll
  for (int ct = 0; ct < 4; ++ct) {
#pragma unroll
    for (int r = 0; r < 16; ++r) {
      int q = (r & 3) + 8 * (r >> 2) + 4 * hi;     // C/D row map (m74/m101)
      Op[(size_t)q * 128 + ct * 32 + ln31] = f2bf(acc[ct][r]);
    }
  }
}

// ---------------------------------------------------------------- kernel 3
template<int NKS>
__global__ __launch_bounds__(256) void combine(
    const u16* __restrict__ Ob, const float* __restrict__ Lp,
    const float* __restrict__ x, const float* __restrict__ gamma,
    float* __restrict__ out)
{
  int i    = blockIdx.x * 256 + threadIdx.x;   // 0..262143
  int nrow = i >> 4;
  int c0   = (i & 15) << 3;

  float wsum = 0.f;
#pragma unroll
  for (int p = 0; p < NKS; ++p) wsum += Lp[(size_t)p * 16384 + nrow];
  float inv = gamma[0] / wsum;

  size_t off = (size_t)nrow * 128 + c0;
  float accv[8];
#pragma unroll
  for (int j = 0; j < 8; ++j) accv[j] = 0.f;
#pragma unroll
  for (int p = 0; p < NKS; ++p) {
    short8 v = *(const short8*)(Ob + (size_t)p * 16384 * 128 + off);
#pragma unroll
    for (int j = 0; j < 8; ++j) accv[j] += bf2f((u16)v[j]);
  }
  float4 xa = *(const float4*)(x + off);
  float4 xb = *(const float4*)(x + off + 4);
  float4 ra, rb;
  ra.x = fmaf(accv[0], inv, xa.x); ra.y = fmaf(accv[1], inv, xa.y);
  ra.z = fmaf(accv[2], inv, xa.z); ra.w = fmaf(accv[3], inv, xa.w);
  rb.x = fmaf(accv[4], inv, xb.x); rb.y = fmaf(accv[5], inv, xb.y);
  rb.z = fmaf(accv[6], inv, xb.z); rb.w = fmaf(accv[7], inv, xb.w);
  *(float4*)(out + off)     = ra;
  *(float4*)(out + off + 4) = rb;
}

// ---------------------------------------------------------------- launch
extern "C" void kernel_launch(void* const* d_in, const int* in_sizes, int n_in,
                              void* d_out, int out_size, void* d_ws, size_t ws_size,
                              hipStream_t stream)
{
  const float* x  = (const float*)d_in[0];
  const float* wq = (const float*)d_in[1];
  const float* bq = (const float*)d_in[2];
  const float* wk = (const float*)d_in[3];
  const float* bk = (const float*)d_in[4];
  const float* wv = (const float*)d_in[5];
  const float* bv = (const float*)d_in[6];
  const float* gm = (const float*)d_in[7];

  // ws layout:
  //  [0, 512K)    Qb bf16 [4][4096][16]   (pre-scaled by log2e)
  //  [512K, 1M)   Kb bf16 [4][4096][16]
  //  [1M, 5M)     Vt bf16 [4][128][4096]
  //  [5M, ...)    Ob bf16 [NKS][4][4096][128]  (4 MB per split)
  //  after Ob:    Lp f32  [NKS][16384]
  char* w = (char*)d_ws;
  u16*   Qb = (u16*)(w);
  u16*   Kb = (u16*)(w + (512ll << 10));
  u16*   Vt = (u16*)(w + (1ll << 20));
  u16*   Ob = (u16*)(w + (5ll << 20));
  float* out = (float*)d_out;

  qkv_proj<<<128, 256, 0, stream>>>(x, wq, bq, wk, bk, wv, bv, Qb, Kb, Vt);

  const size_t need8 = (5ll << 20) + 8ll * (4ll << 20) + 8ll * 16384 * 4;
  if (ws_size >= need8) {
    float* Lp = (float*)(w + (5ll << 20) + 8ll * (4ll << 20));
    attn<8><<<1024, 256, 0, stream>>>(Qb, Kb, Vt, Ob, Lp);
    combine<8><<<1024, 256, 0, stream>>>(Ob, Lp, x, gm, out);
  } else {
    float* Lp = (float*)(w + (5ll << 20) + 4ll * (4ll << 20));
    attn<4><<<512, 256, 0, stream>>>(Qb, Kb, Vt, Ob, Lp);
    combine<4><<<1024, 256, 0, stream>>>(Ob, Lp, x, gm, out);
  }
}

// Round 9
// 53.448 us; speedup vs baseline: 2.9931x; 2.9931x over previous
//
#include <hip/hip_runtime.h>
#include <hip/hip_bf16.h>

// SAGAN self-attention, MI355X (gfx950).
// B=4, H=W=64 (N=4096), C=128, d_qk=16. out = gamma * softmax(QK^T) V + x.
//
//  k1 qkv_proj : MFMA GEMM x[16384,128] @ [wq|wk|wv] -> Qb,Kb bf16 [4,4096,16],
//                Vt bf16 [4,128,4096]. Q pre-scaled by log2(e). Grid 256
//                (output-tile half-split) to fill all CUs.
//  k2 attn     : flash attention, mfma_f32_32x32x16_bf16, swapped QK^T.
//                No max tracking: p = exp2(s - 16) (|s·log2e| << 127, softmax
//                shift-invariant; bias folded into QK MFMA C operand).
//                exp2f BUILTIN (raw v_exp_f32 asm caused the R8 NaN: trans-op
//                hazard nops aren't inserted around opaque inline asm).
//                V reg-staged dbuf into 144B-row LDS (0 bank conflicts);
//                K single-buffered global->reg. Pairwise exp+pack keeps regs
//                ~160 total -> 3 waves/SIMD (launch_bounds(256,3)).
//                NKS=6 k-split, grid 768 = exactly 3 blocks/CU.
//  k3 combine  : out = gamma * (sum_p O_p) / (sum_p l_p) + x.

typedef __attribute__((ext_vector_type(4)))  short short4v;
typedef __attribute__((ext_vector_type(8)))  short short8;
typedef __attribute__((ext_vector_type(16))) float f32x16;
typedef unsigned short u16;

#define LOG2E 1.4426950408889634f

__device__ __forceinline__ u16 f2bf(float f) {
  __hip_bfloat16 h = __float2bfloat16(f);
  return __builtin_bit_cast(u16, h);
}
__device__ __forceinline__ float bf2f(u16 u) {
  unsigned v = (unsigned)u << 16;
  return __builtin_bit_cast(float, v);
}
// pack two positive f32 -> bf16x2 (round-half-up): 2 adds + 1 v_perm
__device__ __forceinline__ unsigned pkbf(float lo, float hi) {
  unsigned a = __builtin_bit_cast(unsigned, lo) + 0x8000u;
  unsigned b = __builtin_bit_cast(unsigned, hi) + 0x8000u;
  unsigned r;
  asm("v_perm_b32 %0, %1, %2, %3" : "=v"(r) : "v"(b), "v"(a), "s"(0x07060302u));
  return r;   // lo_bf16 | hi_bf16<<16
}
// cross-half (lane i <-> i+32) sum via permlane32_swap: pure VALU
__device__ __forceinline__ float xhalf_sum(float x) {
  float a = x, b = x;
  asm("v_permlane32_swap_b32 %0, %1" : "+v"(a), "+v"(b));
  return a + b;
}

// ---------------------------------------------------------------- kernel 1
// grid 256 = b(4) x rt(32) x half(2): block computes rows [rt*128,+128),
// half 0 -> Q,K + V cols 0..63 (12 tiles), half 1 -> V cols 64..127 (8 tiles).
__global__ __launch_bounds__(256) void qkv_proj(
    const float* __restrict__ x,
    const float* __restrict__ wq, const float* __restrict__ bq,
    const float* __restrict__ wk, const float* __restrict__ bk,
    const float* __restrict__ wv, const float* __restrict__ bv,
    u16* __restrict__ Qb, u16* __restrict__ Kb, u16* __restrict__ Vt)
{
  __shared__ u16 xs[128 * 136];
  __shared__ u16 ws[160 * 136];
  const int tid  = threadIdx.x;
  const int b    = blockIdx.x >> 6;
  const int n0   = ((blockIdx.x >> 1) & 31) * 128;
  const int half = blockIdx.x & 1;

  const float4* xg = (const float4*)(x + ((size_t)b * 4096 + n0) * 128);
#pragma unroll
  for (int p = 0; p < 16; ++p) {
    int idx = tid + p * 256;              // 4096 float4s
    float4 v = xg[idx];
    int n = idx >> 5, i4 = idx & 31;
    short4v pk;
    pk[0] = (short)f2bf(v.x); pk[1] = (short)f2bf(v.y);
    pk[2] = (short)f2bf(v.z); pk[3] = (short)f2bf(v.w);
    *(short4v*)(xs + n * 136 + i4 * 4) = pk;
  }
  if (half == 0) {
#pragma unroll
    for (int p = 0; p < 8; ++p) {
      int idx = tid + p * 256;            // 2048 = 128x16
      int k = idx >> 4, d = idx & 15;
      ws[d * 136 + k]        = f2bf(wq[idx] * LOG2E);
      ws[(16 + d) * 136 + k] = f2bf(wk[idx]);
    }
#pragma unroll
    for (int p = 0; p < 32; ++p) {
      int idx = tid + p * 256;            // 8192 = 128k x 64c (cols 0..63)
      int k = idx >> 6, c = idx & 63;
      ws[(32 + c) * 136 + k] = f2bf(wv[k * 128 + c]);
    }
  } else {
#pragma unroll
    for (int p = 0; p < 32; ++p) {
      int idx = tid + p * 256;            // cols 64..127
      int k = idx >> 6, c = 64 + (idx & 63);
      ws[(32 + c) * 136 + k] = f2bf(wv[k * 128 + c]);
    }
  }
  __syncthreads();

  const int lane = tid & 63, wid = tid >> 6;
  const int ln31 = lane & 31, hi = lane >> 5;
  const int NJ = half ? 2 : 3;

#pragma unroll 1
  for (int j = 0; j < NJ; ++j) {
    int t = wid + j * 4;
    int mt, nt;
    if (half == 0) { mt = t / 3; nt = t % 3; }
    else           { mt = t >> 1; nt = 3 + (t & 1); }
    const u16* arow = xs + (mt * 32 + ln31) * 136 + hi * 8;
    const u16* brow = ws + (nt * 32 + ln31) * 136 + hi * 8;
    f32x16 acc = (f32x16)0.0f;
#pragma unroll
    for (int ks = 0; ks < 8; ++ks) {
      short8 a = *(const short8*)(arow + ks * 16);
      short8 w = *(const short8*)(brow + ks * 16);
      acc = __builtin_amdgcn_mfma_f32_32x32x16_bf16(a, w, acc, 0, 0, 0);
    }
    if (nt == 0) {
      float bias = (ln31 < 16) ? bq[ln31] * LOG2E : bk[ln31 & 15];
      u16* base = ((ln31 < 16) ? Qb : Kb)
                + ((size_t)b * 4096 + n0 + mt * 32) * 16 + (ln31 & 15);
#pragma unroll
      for (int r = 0; r < 16; ++r) {
        int nl = (r & 3) + 8 * (r >> 2) + 4 * hi;   // C/D row map
        base[nl * 16] = f2bf(acc[r] + bias);
      }
    } else {
      int c = (nt - 1) * 32 + ln31;
      float bias = bv[c];
      u16* vb = Vt + ((size_t)b * 128 + c) * 4096 + n0 + mt * 32 + 4 * hi;
#pragma unroll
      for (int g = 0; g < 4; ++g) {
        short4v pk;
        pk[0] = (short)f2bf(acc[g*4+0] + bias);
        pk[1] = (short)f2bf(acc[g*4+1] + bias);
        pk[2] = (short)f2bf(acc[g*4+2] + bias);
        pk[3] = (short)f2bf(acc[g*4+3] + bias);
        *(short4v*)(vb + 8 * g) = pk;
      }
    }
  }
}

// ---------------------------------------------------------------- kernel 2
// grid 4*32*NKS. block 256 = 4 waves, wave owns 32 q-rows (128 q/block).
// Block ks handles 64-k chunks [ks*64/NKS, (ks+1)*64/NKS).
// Partials: Ob bf16 [NKS][4][4096][128], Lp f32 [NKS][16384].
template<int NKS>
__global__ __launch_bounds__(256, 3) void attn(
    const u16* __restrict__ Qb, const u16* __restrict__ Kb,
    const u16* __restrict__ Vt,
    u16* __restrict__ Ob, float* __restrict__ Lp)
{
  // per buffer: V 128 rows x 144B (64 k bf16 + 16B pad) = 18432
  __shared__ __align__(16) char sm[2][18432];
  const int tid  = threadIdx.x;
  const int lane = tid & 63;
  const int wid  = tid >> 6;
  const int ln31 = lane & 31;
  const int hi   = lane >> 5;

  const int bx   = blockIdx.x;
  const int ks   = bx % NKS;
  const int rest = bx / NKS;
  const int b    = rest >> 5;
  const int qt   = rest & 31;
  const int qw   = qt * 128 + wid * 32;   // wave's first q row (within batch)
  const int c0   = (ks * 64) / NKS;       // chunk range [c0, c1)
  const int c1   = ((ks + 1) * 64) / NKS;

  // Q B-fragment: col q = ln31, d = hi*8 + j (Q pre-scaled by log2e)
  const short8 qf = *(const short8*)(Qb + (((size_t)b * 4096 + qw + ln31) << 4) + (hi << 3));

  f32x16 acc[4];
#pragma unroll
  for (int ct = 0; ct < 4; ++ct) acc[ct] = (f32x16)0.0f;
  float lacc = 0.f;
  const f32x16 cbias = (f32x16)(-16.0f);  // s = q.k*log2e - 16, free in MFMA C

  const char* vg = (const char*)(Vt + (size_t)b * 128 * 4096);
  const char* kg = (const char*)(Kb + (size_t)b * 4096 * 16);
  const int vc = tid >> 1;                // V channel row this thread stages
  const int vp = tid & 1;                 // which 64B half of the 128B row

  uint4 rv0, rv1, rv2, rv3;               // V staging regs (T14 split)
  uint4 rk0, rk1;                         // K fragments, single-buffered

  auto loadV = [&](int kb) {              // global -> regs (issued early)
    const char* vs = vg + (size_t)vc * 8192 + (size_t)kb * 2 + vp * 64;
    rv0 = *(const uint4*)(vs);
    rv1 = *(const uint4*)(vs + 16);
    rv2 = *(const uint4*)(vs + 32);
    rv3 = *(const uint4*)(vs + 48);
  };
  auto loadK = [&](int kb) {              // direct to regs, coalesced (L2-hot)
    const char* kr = kg + (size_t)(kb + ln31) * 32 + hi * 16;
    rk0 = *(const uint4*)(kr);            // kt=0 rows
    rk1 = *(const uint4*)(kr + 1024);     // kt=1 rows
  };
  auto storeV = [&](char* buf) {          // regs -> LDS (after compute)
    char* vd = buf + vc * 144 + vp * 64;
    *(uint4*)(vd)      = rv0;
    *(uint4*)(vd + 16) = rv1;
    *(uint4*)(vd + 32) = rv2;
    *(uint4*)(vd + 48) = rv3;
  };

  auto compute = [&](const char* buf) {
#pragma unroll
    for (int kt = 0; kt < 2; ++kt) {      // two independent 32-k subtiles
      // swapped QK^T: A = K rows (kk = ln31), B = Q -> D[kk][q], lane col = q
      short8 kf = __builtin_bit_cast(short8, kt ? rk1 : rk0);
      f32x16 s = __builtin_amdgcn_mfma_f32_32x32x16_bf16(kf, qf, cbias, 0, 0, 0);

      // p = exp2(s), pairwise (keeps live ranges small); s[r] is
      // kk = (r&3)+8*(r>>2)+4*hi for this lane's q-row (q = ln31).
      float e0 = exp2f(s[0]),  e1 = exp2f(s[1]);
      unsigned u0 = pkbf(e0, e1);  float t0 = e0 + e1;
      float e2 = exp2f(s[2]),  e3 = exp2f(s[3]);
      unsigned u1 = pkbf(e2, e3);  float t1 = e2 + e3;
      float e4 = exp2f(s[4]),  e5 = exp2f(s[5]);
      unsigned u2 = pkbf(e4, e5);  float t2 = e4 + e5;
      float e6 = exp2f(s[6]),  e7 = exp2f(s[7]);
      unsigned u3 = pkbf(e6, e7);  float t3 = e6 + e7;
      float e8 = exp2f(s[8]),  e9 = exp2f(s[9]);
      unsigned y0 = pkbf(e8, e9);  float t4 = e8 + e9;
      float ea = exp2f(s[10]), eb = exp2f(s[11]);
      unsigned y1 = pkbf(ea, eb);  float t5 = ea + eb;
      float ec = exp2f(s[12]), ed = exp2f(s[13]);
      unsigned y2 = pkbf(ec, ed);  float t6 = ec + ed;
      float ee = exp2f(s[14]), ef = exp2f(s[15]);
      unsigned y3 = pkbf(ee, ef);  float t7 = ee + ef;
      lacc += ((t0 + t1) + (t2 + t3)) + ((t4 + t5) + (t6 + t7));

      // P -> bf16 PV A-fragments via permlane32_swap (T12)
      asm("v_permlane32_swap_b32 %0, %1" : "+v"(u0), "+v"(u2));
      asm("v_permlane32_swap_b32 %0, %1" : "+v"(u1), "+v"(u3));
      asm("v_permlane32_swap_b32 %0, %1" : "+v"(y0), "+v"(y2));
      asm("v_permlane32_swap_b32 %0, %1" : "+v"(y1), "+v"(y3));
      union { unsigned u[4]; short8 s8; } pa0, pa1;
      pa0.u[0] = u0; pa0.u[1] = u1; pa0.u[2] = u2; pa0.u[3] = u3;
      pa1.u[0] = y0; pa1.u[1] = y1; pa1.u[2] = y2; pa1.u[3] = y3;

      // PV: acc[ct] += P[32q x 32k] @ V[32k x 32c] (two K=16 MFMAs per ct)
      __builtin_amdgcn_s_setprio(1);
#pragma unroll
      for (int ct = 0; ct < 4; ++ct) {
        const char* vrow = buf + (ct * 32 + ln31) * 144 + kt * 64 + hi * 16;
        short8 vf0 = *(const short8*)(vrow);        // k 0..15 of subtile
        short8 vf1 = *(const short8*)(vrow + 32);   // k 16..31
        acc[ct] = __builtin_amdgcn_mfma_f32_32x32x16_bf16(pa0.s8, vf0, acc[ct], 0, 0, 0);
        acc[ct] = __builtin_amdgcn_mfma_f32_32x32x16_bf16(pa1.s8, vf1, acc[ct], 0, 0, 0);
      }
      __builtin_amdgcn_s_setprio(0);
    }
  };

  loadV(c0 * 64);
  storeV(sm[0]);
  __syncthreads();
  int cur = 0;
#pragma unroll 1
  for (int it = c0; it < c1; ++it) {
    loadK(it * 64);                       // K first: its waitcnt leaves V in flight
    if (it < c1 - 1) loadV((it + 1) * 64);
    compute(sm[cur]);
    if (it < c1 - 1) storeV(sm[cur ^ 1]);
    __syncthreads();                      // single barrier per iter (dbuf)
    cur ^= 1;
  }

  // epilogue: cross-half l reduce, store bf16 partial O and l
  float lt = xhalf_sum(lacc);
  if (lane < 32)
    Lp[(size_t)ks * 16384 + (size_t)b * 4096 + qw + lane] = lt;
  u16* Op = Ob + ((size_t)ks * 16384 + (size_t)b * 4096 + qw) * 128;
#pragma unroll
  for (int ct = 0; ct < 4; ++ct) {
#pragma unroll
    for (int r = 0; r < 16; ++r) {
      int q = (r & 3) + 8 * (r >> 2) + 4 * hi;     // C/D row map (m74/m101)
      Op[(size_t)q * 128 + ct * 32 + ln31] = f2bf(acc[ct][r]);
    }
  }
}

// ---------------------------------------------------------------- kernel 3
template<int NKS>
__global__ __launch_bounds__(256) void combine(
    const u16* __restrict__ Ob, const float* __restrict__ Lp,
    const float* __restrict__ x, const float* __restrict__ gamma,
    float* __restrict__ out)
{
  int i    = blockIdx.x * 256 + threadIdx.x;   // 0..262143
  int nrow = i >> 4;
  int c0   = (i & 15) << 3;

  float wsum = 0.f;
#pragma unroll
  for (int p = 0; p < NKS; ++p) wsum += Lp[(size_t)p * 16384 + nrow];
  float inv = gamma[0] / wsum;

  size_t off = (size_t)nrow * 128 + c0;
  float accv[8];
#pragma unroll
  for (int j = 0; j < 8; ++j) accv[j] = 0.f;
#pragma unroll
  for (int p = 0; p < NKS; ++p) {
    short8 v = *(const short8*)(Ob + (size_t)p * 16384 * 128 + off);
#pragma unroll
    for (int j = 0; j < 8; ++j) accv[j] += bf2f((u16)v[j]);
  }
  float4 xa = *(const float4*)(x + off);
  float4 xb = *(const float4*)(x + off + 4);
  float4 ra, rb;
  ra.x = fmaf(accv[0], inv, xa.x); ra.y = fmaf(accv[1], inv, xa.y);
  ra.z = fmaf(accv[2], inv, xa.z); ra.w = fmaf(accv[3], inv, xa.w);
  rb.x = fmaf(accv[4], inv, xb.x); rb.y = fmaf(accv[5], inv, xb.y);
  rb.z = fmaf(accv[6], inv, xb.z); rb.w = fmaf(accv[7], inv, xb.w);
  *(float4*)(out + off)     = ra;
  *(float4*)(out + off + 4) = rb;
}

// ---------------------------------------------------------------- launch
extern "C" void kernel_launch(void* const* d_in, const int* in_sizes, int n_in,
                              void* d_out, int out_size, void* d_ws, size_t ws_size,
                              hipStream_t stream)
{
  const float* x  = (const float*)d_in[0];
  const float* wq = (const float*)d_in[1];
  const float* bq = (const float*)d_in[2];
  const float* wk = (const float*)d_in[3];
  const float* bk = (const float*)d_in[4];
  const float* wv = (const float*)d_in[5];
  const float* bv = (const float*)d_in[6];
  const float* gm = (const float*)d_in[7];

  // ws layout:
  //  [0, 512K)    Qb bf16 [4][4096][16]   (pre-scaled by log2e)
  //  [512K, 1M)   Kb bf16 [4][4096][16]
  //  [1M, 5M)     Vt bf16 [4][128][4096]
  //  [5M, ...)    Ob bf16 [NKS][4][4096][128]  (4 MB per split)
  //  after Ob:    Lp f32  [NKS][16384]
  char* w = (char*)d_ws;
  u16*   Qb = (u16*)(w);
  u16*   Kb = (u16*)(w + (512ll << 10));
  u16*   Vt = (u16*)(w + (1ll << 20));
  u16*   Ob = (u16*)(w + (5ll << 20));
  float* out = (float*)d_out;

  qkv_proj<<<256, 256, 0, stream>>>(x, wq, bq, wk, bk, wv, bv, Qb, Kb, Vt);

  const size_t need6 = (5ll << 20) + 6ll * (4ll << 20) + 6ll * 16384 * 4;
  if (ws_size >= need6) {
    float* Lp = (float*)(w + (5ll << 20) + 6ll * (4ll << 20));
    attn<6><<<768, 256, 0, stream>>>(Qb, Kb, Vt, Ob, Lp);
    combine<6><<<1024, 256, 0, stream>>>(Ob, Lp, x, gm, out);
  } else {
    float* Lp = (float*)(w + (5ll << 20) + 2ll * (4ll << 20));
    attn<2><<<256, 256, 0, stream>>>(Qb, Kb, Vt, Ob, Lp);
    combine<2><<<1024, 256, 0, stream>>>(Ob, Lp, x, gm, out);
  }
}

// Round 10
// 47.278 us; speedup vs baseline: 3.3836x; 1.1305x over previous
//
#include <hip/hip_runtime.h>
#include <hip/hip_bf16.h>

// SAGAN self-attention, MI355X (gfx950).
// B=4, H=W=64 (N=4096), C=128, d_qk=16. out = gamma * softmax(QK^T) V + x.
//
//  k1 qkv_proj : MFMA GEMM x[16384,128] @ [wq|wk|wv] -> Qb,Kb bf16 [4,4096,16],
//                Vt bf16 [4,128,4096]. Q pre-scaled by log2(e). Grid 256.
//  k2 attn     : flash attention, mfma_f32_32x32x16_bf16, swapped QK^T.
//                No max tracking: p = exp2(s - 16) (|s·log2e| << 127, softmax
//                shift-invariant; bias folded into QK MFMA C operand).
//                exp2 via __builtin_amdgcn_exp2f: single v_exp_f32 WITH
//                compiler hazard handling (raw asm NaN'd in R8; libm exp2f
//                adds a denormal guard we can't hit since s >= -56).
//                V reg-staged dbuf into 144B-row LDS (0 bank conflicts);
//                K reg double-buffered (prefetched 1 chunk ahead -> L2 latency
//                off the critical path). ~148 total regs -> 3 waves/SIMD.
//                NKS=6 k-split, grid 768 = exactly 3 blocks/CU.
//  k3 combine  : out = gamma * (sum_p O_p) / (sum_p l_p) + x.

typedef __attribute__((ext_vector_type(4)))  short short4v;
typedef __attribute__((ext_vector_type(8)))  short short8;
typedef __attribute__((ext_vector_type(16))) float f32x16;
typedef unsigned short u16;

#define LOG2E 1.4426950408889634f

__device__ __forceinline__ u16 f2bf(float f) {
  __hip_bfloat16 h = __float2bfloat16(f);
  return __builtin_bit_cast(u16, h);
}
// fast bf16 (round-half-up) for partial-O stores: 2 VALU ops
__device__ __forceinline__ u16 f2bf_fast(float f) {
  unsigned u = __builtin_bit_cast(unsigned, f) + 0x8000u;
  return (u16)(u >> 16);
}
__device__ __forceinline__ float bf2f(u16 u) {
  unsigned v = (unsigned)u << 16;
  return __builtin_bit_cast(float, v);
}
// single-instruction 2^x (inputs bounded away from denormal range)
__device__ __forceinline__ float fexp2(float x) {
#if __has_builtin(__builtin_amdgcn_exp2f)
  return __builtin_amdgcn_exp2f(x);
#else
  return exp2f(x);
#endif
}
// pack two positive f32 -> bf16x2 (round-half-up): 2 adds + 1 v_perm
__device__ __forceinline__ unsigned pkbf(float lo, float hi) {
  unsigned a = __builtin_bit_cast(unsigned, lo) + 0x8000u;
  unsigned b = __builtin_bit_cast(unsigned, hi) + 0x8000u;
  unsigned r;
  asm("v_perm_b32 %0, %1, %2, %3" : "=v"(r) : "v"(b), "v"(a), "s"(0x07060302u));
  return r;   // lo_bf16 | hi_bf16<<16
}
// cross-half (lane i <-> i+32) sum via permlane32_swap: pure VALU
__device__ __forceinline__ float xhalf_sum(float x) {
  float a = x, b = x;
  asm("v_permlane32_swap_b32 %0, %1" : "+v"(a), "+v"(b));
  return a + b;
}

// ---------------------------------------------------------------- kernel 1
// grid 256 = b(4) x rt(32) x half(2): block computes rows [rt*128,+128),
// half 0 -> Q,K + V cols 0..63 (12 tiles), half 1 -> V cols 64..127 (8 tiles).
__global__ __launch_bounds__(256) void qkv_proj(
    const float* __restrict__ x,
    const float* __restrict__ wq, const float* __restrict__ bq,
    const float* __restrict__ wk, const float* __restrict__ bk,
    const float* __restrict__ wv, const float* __restrict__ bv,
    u16* __restrict__ Qb, u16* __restrict__ Kb, u16* __restrict__ Vt)
{
  __shared__ u16 xs[128 * 136];
  __shared__ u16 ws[160 * 136];
  const int tid  = threadIdx.x;
  const int b    = blockIdx.x >> 6;
  const int n0   = ((blockIdx.x >> 1) & 31) * 128;
  const int half = blockIdx.x & 1;

  const float4* xg = (const float4*)(x + ((size_t)b * 4096 + n0) * 128);
#pragma unroll
  for (int p = 0; p < 16; ++p) {
    int idx = tid + p * 256;              // 4096 float4s
    float4 v = xg[idx];
    int n = idx >> 5, i4 = idx & 31;
    short4v pk;
    pk[0] = (short)f2bf(v.x); pk[1] = (short)f2bf(v.y);
    pk[2] = (short)f2bf(v.z); pk[3] = (short)f2bf(v.w);
    *(short4v*)(xs + n * 136 + i4 * 4) = pk;
  }
  if (half == 0) {
#pragma unroll
    for (int p = 0; p < 8; ++p) {
      int idx = tid + p * 256;            // 2048 = 128x16
      int k = idx >> 4, d = idx & 15;
      ws[d * 136 + k]        = f2bf(wq[idx] * LOG2E);
      ws[(16 + d) * 136 + k] = f2bf(wk[idx]);
    }
#pragma unroll
    for (int p = 0; p < 32; ++p) {
      int idx = tid + p * 256;            // 8192 = 128k x 64c (cols 0..63)
      int k = idx >> 6, c = idx & 63;
      ws[(32 + c) * 136 + k] = f2bf(wv[k * 128 + c]);
    }
  } else {
#pragma unroll
    for (int p = 0; p < 32; ++p) {
      int idx = tid + p * 256;            // cols 64..127
      int k = idx >> 6, c = 64 + (idx & 63);
      ws[(32 + c) * 136 + k] = f2bf(wv[k * 128 + c]);
    }
  }
  __syncthreads();

  const int lane = tid & 63, wid = tid >> 6;
  const int ln31 = lane & 31, hi = lane >> 5;
  const int NJ = half ? 2 : 3;

#pragma unroll 1
  for (int j = 0; j < NJ; ++j) {
    int t = wid + j * 4;
    int mt, nt;
    if (half == 0) { mt = t / 3; nt = t % 3; }
    else           { mt = t >> 1; nt = 3 + (t & 1); }
    const u16* arow = xs + (mt * 32 + ln31) * 136 + hi * 8;
    const u16* brow = ws + (nt * 32 + ln31) * 136 + hi * 8;
    f32x16 acc = (f32x16)0.0f;
#pragma unroll
    for (int ks = 0; ks < 8; ++ks) {
      short8 a = *(const short8*)(arow + ks * 16);
      short8 w = *(const short8*)(brow + ks * 16);
      acc = __builtin_amdgcn_mfma_f32_32x32x16_bf16(a, w, acc, 0, 0, 0);
    }
    if (nt == 0) {
      float bias = (ln31 < 16) ? bq[ln31] * LOG2E : bk[ln31 & 15];
      u16* base = ((ln31 < 16) ? Qb : Kb)
                + ((size_t)b * 4096 + n0 + mt * 32) * 16 + (ln31 & 15);
#pragma unroll
      for (int r = 0; r < 16; ++r) {
        int nl = (r & 3) + 8 * (r >> 2) + 4 * hi;   // C/D row map
        base[nl * 16] = f2bf(acc[r] + bias);
      }
    } else {
      int c = (nt - 1) * 32 + ln31;
      float bias = bv[c];
      u16* vb = Vt + ((size_t)b * 128 + c) * 4096 + n0 + mt * 32 + 4 * hi;
#pragma unroll
      for (int g = 0; g < 4; ++g) {
        short4v pk;
        pk[0] = (short)f2bf(acc[g*4+0] + bias);
        pk[1] = (short)f2bf(acc[g*4+1] + bias);
        pk[2] = (short)f2bf(acc[g*4+2] + bias);
        pk[3] = (short)f2bf(acc[g*4+3] + bias);
        *(short4v*)(vb + 8 * g) = pk;
      }
    }
  }
}

// ---------------------------------------------------------------- kernel 2
// grid 4*32*NKS. block 256 = 4 waves, wave owns 32 q-rows (128 q/block).
// Block ks handles 64-k chunks [ks*64/NKS, (ks+1)*64/NKS).
// Partials: Ob bf16 [NKS][4][4096][128], Lp f32 [NKS][16384].
template<int NKS>
__global__ __launch_bounds__(256, 3) void attn(
    const u16* __restrict__ Qb, const u16* __restrict__ Kb,
    const u16* __restrict__ Vt,
    u16* __restrict__ Ob, float* __restrict__ Lp)
{
  // per buffer: V 128 rows x 144B (64 k bf16 + 16B pad) = 18432
  __shared__ __align__(16) char sm[2][18432];
  const int tid  = threadIdx.x;
  const int lane = tid & 63;
  const int wid  = tid >> 6;
  const int ln31 = lane & 31;
  const int hi   = lane >> 5;

  const int bx   = blockIdx.x;
  const int ks   = bx % NKS;
  const int rest = bx / NKS;
  const int b    = rest >> 5;
  const int qt   = rest & 31;
  const int qw   = qt * 128 + wid * 32;   // wave's first q row (within batch)
  const int c0   = (ks * 64) / NKS;       // chunk range [c0, c1)
  const int c1   = ((ks + 1) * 64) / NKS;

  // Q B-fragment: col q = ln31, d = hi*8 + j (Q pre-scaled by log2e)
  const short8 qf = *(const short8*)(Qb + (((size_t)b * 4096 + qw + ln31) << 4) + (hi << 3));

  f32x16 acc[4];
#pragma unroll
  for (int ct = 0; ct < 4; ++ct) acc[ct] = (f32x16)0.0f;
  float lacc = 0.f;
  const f32x16 cbias = (f32x16)(-16.0f);  // s = q.k*log2e - 16, free in MFMA C

  const char* vg = (const char*)(Vt + (size_t)b * 128 * 4096);
  const char* kg = (const char*)(Kb + (size_t)b * 4096 * 16);
  const int vc = tid >> 1;                // V channel row this thread stages
  const int vp = tid & 1;                 // which 64B half of the 128B row

  uint4 rv0, rv1, rv2, rv3;               // V staging regs (T14 split)
  uint4 rkc0, rkc1, rkn0, rkn1;           // K fragments: current / next (dbuf)

  auto loadV = [&](int kb) {              // global -> regs (issued early)
    const char* vs = vg + (size_t)vc * 8192 + (size_t)kb * 2 + vp * 64;
    rv0 = *(const uint4*)(vs);
    rv1 = *(const uint4*)(vs + 16);
    rv2 = *(const uint4*)(vs + 32);
    rv3 = *(const uint4*)(vs + 48);
  };
  auto loadK = [&](int kb, uint4& k0, uint4& k1) {  // coalesced, L2-hot
    const char* kr = kg + (size_t)(kb + ln31) * 32 + hi * 16;
    k0 = *(const uint4*)(kr);             // kt=0 rows
    k1 = *(const uint4*)(kr + 1024);      // kt=1 rows
  };
  auto storeV = [&](char* buf) {          // regs -> LDS (after compute)
    char* vd = buf + vc * 144 + vp * 64;
    *(uint4*)(vd)      = rv0;
    *(uint4*)(vd + 16) = rv1;
    *(uint4*)(vd + 32) = rv2;
    *(uint4*)(vd + 48) = rv3;
  };

  auto compute = [&](const char* buf, uint4 k0, uint4 k1) {
#pragma unroll
    for (int kt = 0; kt < 2; ++kt) {      // two independent 32-k subtiles
      // swapped QK^T: A = K rows (kk = ln31), B = Q -> D[kk][q], lane col = q
      short8 kf = __builtin_bit_cast(short8, kt ? k1 : k0);
      f32x16 s = __builtin_amdgcn_mfma_f32_32x32x16_bf16(kf, qf, cbias, 0, 0, 0);

      // p = exp2(s), pairwise; s[r] is kk = (r&3)+8*(r>>2)+4*hi for q = ln31.
      float e0 = fexp2(s[0]),  e1 = fexp2(s[1]);
      unsigned u0 = pkbf(e0, e1);  float t0 = e0 + e1;
      float e2 = fexp2(s[2]),  e3 = fexp2(s[3]);
      unsigned u1 = pkbf(e2, e3);  float t1 = e2 + e3;
      float e4 = fexp2(s[4]),  e5 = fexp2(s[5]);
      unsigned u2 = pkbf(e4, e5);  float t2 = e4 + e5;
      float e6 = fexp2(s[6]),  e7 = fexp2(s[7]);
      unsigned u3 = pkbf(e6, e7);  float t3 = e6 + e7;
      float e8 = fexp2(s[8]),  e9 = fexp2(s[9]);
      unsigned y0 = pkbf(e8, e9);  float t4 = e8 + e9;
      float ea = fexp2(s[10]), eb = fexp2(s[11]);
      unsigned y1 = pkbf(ea, eb);  float t5 = ea + eb;
      float ec = fexp2(s[12]), ed = fexp2(s[13]);
      unsigned y2 = pkbf(ec, ed);  float t6 = ec + ed;
      float ee = fexp2(s[14]), ef = fexp2(s[15]);
      unsigned y3 = pkbf(ee, ef);  float t7 = ee + ef;
      lacc += ((t0 + t1) + (t2 + t3)) + ((t4 + t5) + (t6 + t7));

      // P -> bf16 PV A-fragments via permlane32_swap (T12)
      asm("v_permlane32_swap_b32 %0, %1" : "+v"(u0), "+v"(u2));
      asm("v_permlane32_swap_b32 %0, %1" : "+v"(u1), "+v"(u3));
      asm("v_permlane32_swap_b32 %0, %1" : "+v"(y0), "+v"(y2));
      asm("v_permlane32_swap_b32 %0, %1" : "+v"(y1), "+v"(y3));
      union { unsigned u[4]; short8 s8; } pa0, pa1;
      pa0.u[0] = u0; pa0.u[1] = u1; pa0.u[2] = u2; pa0.u[3] = u3;
      pa1.u[0] = y0; pa1.u[1] = y1; pa1.u[2] = y2; pa1.u[3] = y3;

      // PV: acc[ct] += P[32q x 32k] @ V[32k x 32c] (two K=16 MFMAs per ct)
      __builtin_amdgcn_s_setprio(1);
#pragma unroll
      for (int ct = 0; ct < 4; ++ct) {
        const char* vrow = buf + (ct * 32 + ln31) * 144 + kt * 64 + hi * 16;
        short8 vf0 = *(const short8*)(vrow);        // k 0..15 of subtile
        short8 vf1 = *(const short8*)(vrow + 32);   // k 16..31
        acc[ct] = __builtin_amdgcn_mfma_f32_32x32x16_bf16(pa0.s8, vf0, acc[ct], 0, 0, 0);
        acc[ct] = __builtin_amdgcn_mfma_f32_32x32x16_bf16(pa1.s8, vf1, acc[ct], 0, 0, 0);
      }
      __builtin_amdgcn_s_setprio(0);
    }
  };

  loadV(c0 * 64);
  loadK(c0 * 64, rkc0, rkc1);
  storeV(sm[0]);
  __syncthreads();
  int cur = 0;
#pragma unroll 1
  for (int it = c0; it < c1; ++it) {
    if (it < c1 - 1) {                    // prefetch next chunk (V + K) early
      loadV((it + 1) * 64);
      loadK((it + 1) * 64, rkn0, rkn1);
    }
    compute(sm[cur], rkc0, rkc1);
    if (it < c1 - 1) storeV(sm[cur ^ 1]);
    __syncthreads();                      // single barrier per iter (dbuf)
    rkc0 = rkn0; rkc1 = rkn1; cur ^= 1;
  }

  // epilogue: cross-half l reduce, store bf16 partial O and l
  float lt = xhalf_sum(lacc);
  if (lane < 32)
    Lp[(size_t)ks * 16384 + (size_t)b * 4096 + qw + lane] = lt;
  u16* Op = Ob + ((size_t)ks * 16384 + (size_t)b * 4096 + qw) * 128;
#pragma unroll
  for (int ct = 0; ct < 4; ++ct) {
#pragma unroll
    for (int r = 0; r < 16; ++r) {
      int q = (r & 3) + 8 * (r >> 2) + 4 * hi;     // C/D row map (m74/m101)
      Op[(size_t)q * 128 + ct * 32 + ln31] = f2bf_fast(acc[ct][r]);
    }
  }
}

// ---------------------------------------------------------------- kernel 3
template<int NKS>
__global__ __launch_bounds__(256) void combine(
    const u16* __restrict__ Ob, const float* __restrict__ Lp,
    const float* __restrict__ x, const float* __restrict__ gamma,
    float* __restrict__ out)
{
  int i    = blockIdx.x * 256 + threadIdx.x;   // 0..262143
  int nrow = i >> 4;
  int c0   = (i & 15) << 3;

  float wsum = 0.f;
#pragma unroll
  for (int p = 0; p < NKS; ++p) wsum += Lp[(size_t)p * 16384 + nrow];
  float inv = gamma[0] / wsum;

  size_t off = (size_t)nrow * 128 + c0;
  float accv[8];
#pragma unroll
  for (int j = 0; j < 8; ++j) accv[j] = 0.f;
#pragma unroll
  for (int p = 0; p < NKS; ++p) {
    short8 v = *(const short8*)(Ob + (size_t)p * 16384 * 128 + off);
#pragma unroll
    for (int j = 0; j < 8; ++j) accv[j] += bf2f((u16)v[j]);
  }
  float4 xa = *(const float4*)(x + off);
  float4 xb = *(const float4*)(x + off + 4);
  float4 ra, rb;
  ra.x = fmaf(accv[0], inv, xa.x); ra.y = fmaf(accv[1], inv, xa.y);
  ra.z = fmaf(accv[2], inv, xa.z); ra.w = fmaf(accv[3], inv, xa.w);
  rb.x = fmaf(accv[4], inv, xb.x); rb.y = fmaf(accv[5], inv, xb.y);
  rb.z = fmaf(accv[6], inv, xb.z); rb.w = fmaf(accv[7], inv, xb.w);
  *(float4*)(out + off)     = ra;
  *(float4*)(out + off + 4) = rb;
}

// ---------------------------------------------------------------- launch
extern "C" void kernel_launch(void* const* d_in, const int* in_sizes, int n_in,
                              void* d_out, int out_size, void* d_ws, size_t ws_size,
                              hipStream_t stream)
{
  const float* x  = (const float*)d_in[0];
  const float* wq = (const float*)d_in[1];
  const float* bq = (const float*)d_in[2];
  const float* wk = (const float*)d_in[3];
  const float* bk = (const float*)d_in[4];
  const float* wv = (const float*)d_in[5];
  const float* bv = (const float*)d_in[6];
  const float* gm = (const float*)d_in[7];

  // ws layout:
  //  [0, 512K)    Qb bf16 [4][4096][16]   (pre-scaled by log2e)
  //  [512K, 1M)   Kb bf16 [4][4096][16]
  //  [1M, 5M)     Vt bf16 [4][128][4096]
  //  [5M, ...)    Ob bf16 [NKS][4][4096][128]  (4 MB per split)
  //  after Ob:    Lp f32  [NKS][16384]
  char* w = (char*)d_ws;
  u16*   Qb = (u16*)(w);
  u16*   Kb = (u16*)(w + (512ll << 10));
  u16*   Vt = (u16*)(w + (1ll << 20));
  u16*   Ob = (u16*)(w + (5ll << 20));
  float* out = (float*)d_out;

  qkv_proj<<<256, 256, 0, stream>>>(x, wq, bq, wk, bk, wv, bv, Qb, Kb, Vt);

  const size_t need6 = (5ll << 20) + 6ll * (4ll << 20) + 6ll * 16384 * 4;
  if (ws_size >= need6) {
    float* Lp = (float*)(w + (5ll << 20) + 6ll * (4ll << 20));
    attn<6><<<768, 256, 0, stream>>>(Qb, Kb, Vt, Ob, Lp);
    combine<6><<<1024, 256, 0, stream>>>(Ob, Lp, x, gm, out);
  } else {
    float* Lp = (float*)(w + (5ll << 20) + 2ll * (4ll << 20));
    attn<2><<<256, 256, 0, stream>>>(Qb, Kb, Vt, Ob, Lp);
    combine<2><<<1024, 256, 0, stream>>>(Ob, Lp, x, gm, out);
  }
}

// Round 11
// 46.402 us; speedup vs baseline: 3.4475x; 1.0189x over previous
//
#include <hip/hip_runtime.h>
#include <hip/hip_bf16.h>

// SAGAN self-attention, MI355X (gfx950).
// B=4, H=W=64 (N=4096), C=128, d_qk=16. out = gamma * softmax(QK^T) V + x.
//
//  k1 qkv_proj : MFMA GEMM x[16384,128] @ [wq|wk|wv] -> Qb,Kb bf16 [4,4096,16],
//                Vt bf16 [4,128,4096]. Q pre-scaled by log2(e). Grid 256.
//  k2 attn     : flash attention, mfma_f32_32x32x16_bf16, swapped QK^T.
//                No max tracking: p = exp2(s - 16) (|s·log2e| << 127, softmax
//                shift-invariant; bias folded into QK MFMA C operand).
//                T15 double-pipeline: P(it+1) [QK+exp+pack, reg-only] computed
//                after the barrier while PV(it) [LDS+MFMA] heads the loop --
//                the LDS reads issue immediately each iteration, and blocks
//                alternate VALU/LDS phases. exp2 via __builtin_amdgcn_exp2f.
//                V reg-staged dbuf into 144B-row LDS (0 bank conflicts);
//                K single-set reg load (consumed post-barrier same iter).
//                ~150 total regs -> 3 waves/SIMD. NKS=6, grid 768 = 3/CU.
//  k3 combine  : out = gamma * (sum_p O_p) / (sum_p l_p) + x.

typedef __attribute__((ext_vector_type(4)))  short short4v;
typedef __attribute__((ext_vector_type(8)))  short short8;
typedef __attribute__((ext_vector_type(16))) float f32x16;
typedef unsigned short u16;

#define LOG2E 1.4426950408889634f

__device__ __forceinline__ u16 f2bf(float f) {
  __hip_bfloat16 h = __float2bfloat16(f);
  return __builtin_bit_cast(u16, h);
}
// fast bf16 (round-half-up) for partial-O stores: 2 VALU ops
__device__ __forceinline__ u16 f2bf_fast(float f) {
  unsigned u = __builtin_bit_cast(unsigned, f) + 0x8000u;
  return (u16)(u >> 16);
}
__device__ __forceinline__ float bf2f(u16 u) {
  unsigned v = (unsigned)u << 16;
  return __builtin_bit_cast(float, v);
}
// single-instruction 2^x (inputs bounded away from denormal range)
__device__ __forceinline__ float fexp2(float x) {
#if __has_builtin(__builtin_amdgcn_exp2f)
  return __builtin_amdgcn_exp2f(x);
#else
  return exp2f(x);
#endif
}
// pack two positive f32 -> bf16x2 (round-half-up): 2 adds + 1 v_perm
__device__ __forceinline__ unsigned pkbf(float lo, float hi) {
  unsigned a = __builtin_bit_cast(unsigned, lo) + 0x8000u;
  unsigned b = __builtin_bit_cast(unsigned, hi) + 0x8000u;
  unsigned r;
  asm("v_perm_b32 %0, %1, %2, %3" : "=v"(r) : "v"(b), "v"(a), "s"(0x07060302u));
  return r;   // lo_bf16 | hi_bf16<<16
}
// cross-half (lane i <-> i+32) sum via permlane32_swap: pure VALU
__device__ __forceinline__ float xhalf_sum(float x) {
  float a = x, b = x;
  asm("v_permlane32_swap_b32 %0, %1" : "+v"(a), "+v"(b));
  return a + b;
}

// ---------------------------------------------------------------- kernel 1
// grid 256 = b(4) x rt(32) x half(2): block computes rows [rt*128,+128),
// half 0 -> Q,K + V cols 0..63 (12 tiles), half 1 -> V cols 64..127 (8 tiles).
__global__ __launch_bounds__(256) void qkv_proj(
    const float* __restrict__ x,
    const float* __restrict__ wq, const float* __restrict__ bq,
    const float* __restrict__ wk, const float* __restrict__ bk,
    const float* __restrict__ wv, const float* __restrict__ bv,
    u16* __restrict__ Qb, u16* __restrict__ Kb, u16* __restrict__ Vt)
{
  __shared__ u16 xs[128 * 136];
  __shared__ u16 ws[160 * 136];
  const int tid  = threadIdx.x;
  const int b    = blockIdx.x >> 6;
  const int n0   = ((blockIdx.x >> 1) & 31) * 128;
  const int half = blockIdx.x & 1;

  const float4* xg = (const float4*)(x + ((size_t)b * 4096 + n0) * 128);
#pragma unroll
  for (int p = 0; p < 16; ++p) {
    int idx = tid + p * 256;              // 4096 float4s
    float4 v = xg[idx];
    int n = idx >> 5, i4 = idx & 31;
    short4v pk;
    pk[0] = (short)f2bf(v.x); pk[1] = (short)f2bf(v.y);
    pk[2] = (short)f2bf(v.z); pk[3] = (short)f2bf(v.w);
    *(short4v*)(xs + n * 136 + i4 * 4) = pk;
  }
  if (half == 0) {
#pragma unroll
    for (int p = 0; p < 8; ++p) {
      int idx = tid + p * 256;            // 2048 = 128x16
      int k = idx >> 4, d = idx & 15;
      ws[d * 136 + k]        = f2bf(wq[idx] * LOG2E);
      ws[(16 + d) * 136 + k] = f2bf(wk[idx]);
    }
#pragma unroll
    for (int p = 0; p < 32; ++p) {
      int idx = tid + p * 256;            // 8192 = 128k x 64c (cols 0..63)
      int k = idx >> 6, c = idx & 63;
      ws[(32 + c) * 136 + k] = f2bf(wv[k * 128 + c]);
    }
  } else {
#pragma unroll
    for (int p = 0; p < 32; ++p) {
      int idx = tid + p * 256;            // cols 64..127
      int k = idx >> 6, c = 64 + (idx & 63);
      ws[(32 + c) * 136 + k] = f2bf(wv[k * 128 + c]);
    }
  }
  __syncthreads();

  const int lane = tid & 63, wid = tid >> 6;
  const int ln31 = lane & 31, hi = lane >> 5;
  const int NJ = half ? 2 : 3;

#pragma unroll 1
  for (int j = 0; j < NJ; ++j) {
    int t = wid + j * 4;
    int mt, nt;
    if (half == 0) { mt = t / 3; nt = t % 3; }
    else           { mt = t >> 1; nt = 3 + (t & 1); }
    const u16* arow = xs + (mt * 32 + ln31) * 136 + hi * 8;
    const u16* brow = ws + (nt * 32 + ln31) * 136 + hi * 8;
    f32x16 acc = (f32x16)0.0f;
#pragma unroll
    for (int ks = 0; ks < 8; ++ks) {
      short8 a = *(const short8*)(arow + ks * 16);
      short8 w = *(const short8*)(brow + ks * 16);
      acc = __builtin_amdgcn_mfma_f32_32x32x16_bf16(a, w, acc, 0, 0, 0);
    }
    if (nt == 0) {
      float bias = (ln31 < 16) ? bq[ln31] * LOG2E : bk[ln31 & 15];
      u16* base = ((ln31 < 16) ? Qb : Kb)
                + ((size_t)b * 4096 + n0 + mt * 32) * 16 + (ln31 & 15);
#pragma unroll
      for (int r = 0; r < 16; ++r) {
        int nl = (r & 3) + 8 * (r >> 2) + 4 * hi;   // C/D row map
        base[nl * 16] = f2bf(acc[r] + bias);
      }
    } else {
      int c = (nt - 1) * 32 + ln31;
      float bias = bv[c];
      u16* vb = Vt + ((size_t)b * 128 + c) * 4096 + n0 + mt * 32 + 4 * hi;
#pragma unroll
      for (int g = 0; g < 4; ++g) {
        short4v pk;
        pk[0] = (short)f2bf(acc[g*4+0] + bias);
        pk[1] = (short)f2bf(acc[g*4+1] + bias);
        pk[2] = (short)f2bf(acc[g*4+2] + bias);
        pk[3] = (short)f2bf(acc[g*4+3] + bias);
        *(short4v*)(vb + 8 * g) = pk;
      }
    }
  }
}

// ---------------------------------------------------------------- kernel 2
// grid 4*32*NKS. block 256 = 4 waves, wave owns 32 q-rows (128 q/block).
// Block ks handles 64-k chunks [ks*64/NKS, (ks+1)*64/NKS).
// Partials: Ob bf16 [NKS][4][4096][128], Lp f32 [NKS][16384].
template<int NKS>
__global__ __launch_bounds__(256, 3) void attn(
    const u16* __restrict__ Qb, const u16* __restrict__ Kb,
    const u16* __restrict__ Vt,
    u16* __restrict__ Ob, float* __restrict__ Lp)
{
  // per buffer: V 128 rows x 144B (64 k bf16 + 16B pad) = 18432
  __shared__ __align__(16) char sm[2][18432];
  const int tid  = threadIdx.x;
  const int lane = tid & 63;
  const int wid  = tid >> 6;
  const int ln31 = lane & 31;
  const int hi   = lane >> 5;

  const int bx   = blockIdx.x;
  const int ks   = bx % NKS;
  const int rest = bx / NKS;
  const int b    = rest >> 5;
  const int qt   = rest & 31;
  const int qw   = qt * 128 + wid * 32;   // wave's first q row (within batch)
  const int c0   = (ks * 64) / NKS;       // chunk range [c0, c1)
  const int c1   = ((ks + 1) * 64) / NKS;

  // Q B-fragment: col q = ln31, d = hi*8 + j (Q pre-scaled by log2e)
  const short8 qf = *(const short8*)(Qb + (((size_t)b * 4096 + qw + ln31) << 4) + (hi << 3));

  f32x16 acc[4];
#pragma unroll
  for (int ct = 0; ct < 4; ++ct) acc[ct] = (f32x16)0.0f;
  float lacc = 0.f;
  const f32x16 cbias = (f32x16)(-16.0f);  // s = q.k*log2e - 16, free in MFMA C

  const char* vg = (const char*)(Vt + (size_t)b * 128 * 4096);
  const char* kg = (const char*)(Kb + (size_t)b * 4096 * 16);
  const int vc = tid >> 1;                // V channel row this thread stages
  const int vp = tid & 1;                 // which 64B half of the 128B row

  uint4 rv0, rv1, rv2, rv3;               // V staging regs
  uint4 rk0, rk1;                         // K fragments (single set)
  short8 paA0, paA1, paB0, paB1;          // P A-frags for CURRENT chunk
                                          // (kt0:k0-15,k16-31; kt1:k0-15,k16-31)

  auto loadV = [&](int kb) {              // global -> regs (issued early)
    const char* vs = vg + (size_t)vc * 8192 + (size_t)kb * 2 + vp * 64;
    rv0 = *(const uint4*)(vs);
    rv1 = *(const uint4*)(vs + 16);
    rv2 = *(const uint4*)(vs + 32);
    rv3 = *(const uint4*)(vs + 48);
  };
  auto loadK = [&](int kb) {              // coalesced, L2-hot
    const char* kr = kg + (size_t)(kb + ln31) * 32 + hi * 16;
    rk0 = *(const uint4*)(kr);            // kt=0 rows
    rk1 = *(const uint4*)(kr + 1024);     // kt=1 rows
  };
  auto storeV = [&](char* buf) {          // regs -> LDS
    char* vd = buf + vc * 144 + vp * 64;
    *(uint4*)(vd)      = rv0;
    *(uint4*)(vd + 16) = rv1;
    *(uint4*)(vd + 32) = rv2;
    *(uint4*)(vd + 48) = rv3;
  };

  // QK^T + softmax for one chunk: register-only (no LDS). Fills pa frags.
  auto computeP = [&]() {
#pragma unroll
    for (int kt = 0; kt < 2; ++kt) {
      // swapped QK^T: A = K rows (kk = ln31), B = Q -> D[kk][q], lane col = q
      short8 kf = __builtin_bit_cast(short8, kt ? rk1 : rk0);
      f32x16 s = __builtin_amdgcn_mfma_f32_32x32x16_bf16(kf, qf, cbias, 0, 0, 0);

      // p = exp2(s), pairwise; s[r] is kk = (r&3)+8*(r>>2)+4*hi for q = ln31.
      float e0 = fexp2(s[0]),  e1 = fexp2(s[1]);
      unsigned u0 = pkbf(e0, e1);  float t0 = e0 + e1;
      float e2 = fexp2(s[2]),  e3 = fexp2(s[3]);
      unsigned u1 = pkbf(e2, e3);  float t1 = e2 + e3;
      float e4 = fexp2(s[4]),  e5 = fexp2(s[5]);
      unsigned u2 = pkbf(e4, e5);  float t2 = e4 + e5;
      float e6 = fexp2(s[6]),  e7 = fexp2(s[7]);
      unsigned u3 = pkbf(e6, e7);  float t3 = e6 + e7;
      float e8 = fexp2(s[8]),  e9 = fexp2(s[9]);
      unsigned y0 = pkbf(e8, e9);  float t4 = e8 + e9;
      float ea = fexp2(s[10]), eb = fexp2(s[11]);
      unsigned y1 = pkbf(ea, eb);  float t5 = ea + eb;
      float ec = fexp2(s[12]), ed = fexp2(s[13]);
      unsigned y2 = pkbf(ec, ed);  float t6 = ec + ed;
      float ee = fexp2(s[14]), ef = fexp2(s[15]);
      unsigned y3 = pkbf(ee, ef);  float t7 = ee + ef;
      lacc += ((t0 + t1) + (t2 + t3)) + ((t4 + t5) + (t6 + t7));

      // P -> bf16 PV A-fragments via permlane32_swap (T12)
      asm("v_permlane32_swap_b32 %0, %1" : "+v"(u0), "+v"(u2));
      asm("v_permlane32_swap_b32 %0, %1" : "+v"(u1), "+v"(u3));
      asm("v_permlane32_swap_b32 %0, %1" : "+v"(y0), "+v"(y2));
      asm("v_permlane32_swap_b32 %0, %1" : "+v"(y1), "+v"(y3));
      union { unsigned u[4]; short8 s8; } f0, f1;
      f0.u[0] = u0; f0.u[1] = u1; f0.u[2] = u2; f0.u[3] = u3;
      f1.u[0] = y0; f1.u[1] = y1; f1.u[2] = y2; f1.u[3] = y3;
      if (kt == 0) { paA0 = f0.s8; paA1 = f1.s8; }
      else         { paB0 = f0.s8; paB1 = f1.s8; }
    }
  };

  // PV for the current chunk: pure LDS reads + MFMA, issues immediately.
  auto doPV = [&](const char* buf) {
    __builtin_amdgcn_s_setprio(1);
#pragma unroll
    for (int ct = 0; ct < 4; ++ct) {
      const char* vrow = buf + (ct * 32 + ln31) * 144 + hi * 16;
      short8 v00 = *(const short8*)(vrow);        // kt0, k 0..15
      short8 v01 = *(const short8*)(vrow + 32);   // kt0, k 16..31
      short8 v10 = *(const short8*)(vrow + 64);   // kt1, k 0..15
      short8 v11 = *(const short8*)(vrow + 96);   // kt1, k 16..31
      acc[ct] = __builtin_amdgcn_mfma_f32_32x32x16_bf16(paA0, v00, acc[ct], 0, 0, 0);
      acc[ct] = __builtin_amdgcn_mfma_f32_32x32x16_bf16(paA1, v01, acc[ct], 0, 0, 0);
      acc[ct] = __builtin_amdgcn_mfma_f32_32x32x16_bf16(paB0, v10, acc[ct], 0, 0, 0);
      acc[ct] = __builtin_amdgcn_mfma_f32_32x32x16_bf16(paB1, v11, acc[ct], 0, 0, 0);
    }
    __builtin_amdgcn_s_setprio(0);
  };

  // prologue: stage V(c0), compute P(c0)
  loadV(c0 * 64);
  loadK(c0 * 64);
  storeV(sm[0]);
  __syncthreads();
  computeP();
  int cur = 0;
#pragma unroll 1
  for (int it = c0; it < c1; ++it) {
    if (it < c1 - 1) {                    // issue next-chunk loads first
      loadV((it + 1) * 64);
      loadK((it + 1) * 64);
    }
    doPV(sm[cur]);                        // LDS+MFMA phase (P already in regs)
    if (it < c1 - 1) {
      storeV(sm[cur ^ 1]);                // waits only on V loads (vmcnt(2))
      __syncthreads();
      computeP();                         // VALU phase for chunk it+1 (K regs)
    }
    cur ^= 1;
  }

  // epilogue: cross-half l reduce, store bf16 partial O and l
  float lt = xhalf_sum(lacc);
  if (lane < 32)
    Lp[(size_t)ks * 16384 + (size_t)b * 4096 + qw + lane] = lt;
  u16* Op = Ob + ((size_t)ks * 16384 + (size_t)b * 4096 + qw) * 128;
#pragma unroll
  for (int ct = 0; ct < 4; ++ct) {
#pragma unroll
    for (int r = 0; r < 16; ++r) {
      int q = (r & 3) + 8 * (r >> 2) + 4 * hi;     // C/D row map (m74/m101)
      Op[(size_t)q * 128 + ct * 32 + ln31] = f2bf_fast(acc[ct][r]);
    }
  }
}

// ---------------------------------------------------------------- kernel 3
template<int NKS>
__global__ __launch_bounds__(256) void combine(
    const u16* __restrict__ Ob, const float* __restrict__ Lp,
    const float* __restrict__ x, const float* __restrict__ gamma,
    float* __restrict__ out)
{
  int i    = blockIdx.x * 256 + threadIdx.x;   // 0..262143
  int nrow = i >> 4;
  int c0   = (i & 15) << 3;

  float wsum = 0.f;
#pragma unroll
  for (int p = 0; p < NKS; ++p) wsum += Lp[(size_t)p * 16384 + nrow];
  float inv = gamma[0] / wsum;

  size_t off = (size_t)nrow * 128 + c0;
  float accv[8];
#pragma unroll
  for (int j = 0; j < 8; ++j) accv[j] = 0.f;
#pragma unroll
  for (int p = 0; p < NKS; ++p) {
    short8 v = *(const short8*)(Ob + (size_t)p * 16384 * 128 + off);
#pragma unroll
    for (int j = 0; j < 8; ++j) accv[j] += bf2f((u16)v[j]);
  }
  float4 xa = *(const float4*)(x + off);
  float4 xb = *(const float4*)(x + off + 4);
  float4 ra, rb;
  ra.x = fmaf(accv[0], inv, xa.x); ra.y = fmaf(accv[1], inv, xa.y);
  ra.z = fmaf(accv[2], inv, xa.z); ra.w = fmaf(accv[3], inv, xa.w);
  rb.x = fmaf(accv[4], inv, xb.x); rb.y = fmaf(accv[5], inv, xb.y);
  rb.z = fmaf(accv[6], inv, xb.z); rb.w = fmaf(accv[7], inv, xb.w);
  *(float4*)(out + off)     = ra;
  *(float4*)(out + off + 4) = rb;
}

// ---------------------------------------------------------------- launch
extern "C" void kernel_launch(void* const* d_in, const int* in_sizes, int n_in,
                              void* d_out, int out_size, void* d_ws, size_t ws_size,
                              hipStream_t stream)
{
  const float* x  = (const float*)d_in[0];
  const float* wq = (const float*)d_in[1];
  const float* bq = (const float*)d_in[2];
  const float* wk = (const float*)d_in[3];
  const float* bk = (const float*)d_in[4];
  const float* wv = (const float*)d_in[5];
  const float* bv = (const float*)d_in[6];
  const float* gm = (const float*)d_in[7];

  // ws layout:
  //  [0, 512K)    Qb bf16 [4][4096][16]   (pre-scaled by log2e)
  //  [512K, 1M)   Kb bf16 [4][4096][16]
  //  [1M, 5M)     Vt bf16 [4][128][4096]
  //  [5M, ...)    Ob bf16 [NKS][4][4096][128]  (4 MB per split)
  //  after Ob:    Lp f32  [NKS][16384]
  char* w = (char*)d_ws;
  u16*   Qb = (u16*)(w);
  u16*   Kb = (u16*)(w + (512ll << 10));
  u16*   Vt = (u16*)(w + (1ll << 20));
  u16*   Ob = (u16*)(w + (5ll << 20));
  float* out = (float*)d_out;

  qkv_proj<<<256, 256, 0, stream>>>(x, wq, bq, wk, bk, wv, bv, Qb, Kb, Vt);

  const size_t need6 = (5ll << 20) + 6ll * (4ll << 20) + 6ll * 16384 * 4;
  if (ws_size >= need6) {
    float* Lp = (float*)(w + (5ll << 20) + 6ll * (4ll << 20));
    attn<6><<<768, 256, 0, stream>>>(Qb, Kb, Vt, Ob, Lp);
    combine<6><<<1024, 256, 0, stream>>>(Ob, Lp, x, gm, out);
  } else {
    float* Lp = (float*)(w + (5ll << 20) + 2ll * (4ll << 20));
    attn<2><<<256, 256, 0, stream>>>(Qb, Kb, Vt, Ob, Lp);
    combine<2><<<1024, 256, 0, stream>>>(Ob, Lp, x, gm, out);
  }
}